// Round 9
// baseline (5638.097 us; speedup 1.0000x reference)
//
#include <hip/hip_runtime.h>
#include <limits.h>

#define CDIM 256
#define KDIM 8192
#define NROWS 32768
#define THW 8192
#define BNQ 64
#define CAP 16
#define MARGIN 4.0e-4f

typedef __attribute__((ext_vector_type(8))) short short8v;   // 8 bf16 (4 VGPR)
typedef __attribute__((ext_vector_type(4))) float f32x4;
typedef __attribute__((ext_vector_type(4))) unsigned short u16x4;

// ws layout (bytes):
//   [0,       4194304)  W1[k][c] bf16 hi split of w
//   [4194304, 8388608)  W2[k][c] bf16 lo split
//   [8388608, 8519680)  A[n]  np-exact (32768 f32)
//   [8519680, 8552448)  Cq[k] np-exact (8192 f32)
//   [8552448, 8683520)  cnt[n] (32768 i32)
//   [8683520, 9732096)  cand list (32768 x CAP u16)
//   [9732096, 9734144)  loss partials (512 f32)

__device__ __forceinline__ float sq_rn(float a) { return __fmul_rn(a, a); }
__device__ __forceinline__ unsigned short bf16rn(float x) {
    unsigned u = __float_as_uint(x);
    return (unsigned short)((u + 0x7FFFu + ((u >> 16) & 1u)) >> 16);
}
__device__ __forceinline__ float bf16tof(unsigned short h) {
    return __uint_as_float(((unsigned)h) << 16);
}

// numpy pairwise sum of 128 fp32 squares, AVX512 model (verified round 3).
__device__ float pairwise128_sq(const float* __restrict__ p, int stride) {
    float s[16];
#pragma unroll
    for (int l = 0; l < 16; ++l) {
        const float a0 = sq_rn(p[(l)*stride]);
        const float a1 = sq_rn(p[(16 + l) * stride]);
        const float a2 = sq_rn(p[(32 + l) * stride]);
        const float a3 = sq_rn(p[(48 + l) * stride]);
        const float a4 = sq_rn(p[(64 + l) * stride]);
        const float a5 = sq_rn(p[(80 + l) * stride]);
        const float a6 = sq_rn(p[(96 + l) * stride]);
        const float a7 = sq_rn(p[(112 + l) * stride]);
        s[l] = __fadd_rn(__fadd_rn(__fadd_rn(a0, a1), __fadd_rn(a2, a3)),
                         __fadd_rn(__fadd_rn(a4, a5), __fadd_rn(a6, a7)));
    }
    const float u0 = __fadd_rn(__fadd_rn(s[0], s[8]),  __fadd_rn(s[4], s[12]));
    const float u1 = __fadd_rn(__fadd_rn(s[1], s[9]),  __fadd_rn(s[5], s[13]));
    const float u2 = __fadd_rn(__fadd_rn(s[2], s[10]), __fadd_rn(s[6], s[14]));
    const float u3 = __fadd_rn(__fadd_rn(s[3], s[11]), __fadd_rn(s[7], s[15]));
    return __fadd_rn(__fadd_rn(u0, u2), __fadd_rn(u1, u3));
}

__global__ __launch_bounds__(256) void k_A(const float* __restrict__ z,
                                           float* __restrict__ A) {
    const int n = blockIdx.x * 256 + threadIdx.x;
    const float* zp = z + (size_t)(n >> 13) * (CDIM * THW) + (n & (THW - 1));
    const float b0 = pairwise128_sq(zp, THW);
    const float b1 = pairwise128_sq(zp + (size_t)128 * THW, THW);
    A[n] = __fadd_rn(b0, b1);
}

__global__ __launch_bounds__(256) void k_C(const float* __restrict__ w,
                                           float* __restrict__ Cq) {
    const int k = blockIdx.x * 256 + threadIdx.x;
    const float* wp = w + (size_t)k * CDIM;
    Cq[k] = __fadd_rn(pairwise128_sq(wp, 1), pairwise128_sq(wp + 128, 1));
}

// Split w -> bf16 hi/lo, row-major [k][c] (B-operand-friendly).
__global__ __launch_bounds__(256) void k_split(const float* __restrict__ w,
                                               unsigned short* __restrict__ W1,
                                               unsigned short* __restrict__ W2) {
    const int i = blockIdx.x * 256 + threadIdx.x;
    float4 v = *reinterpret_cast<const float4*>(w + (size_t)i * 4);
    const float x[4] = {v.x, v.y, v.z, v.w};
    u16x4 h, lo;
#pragma unroll
    for (int q = 0; q < 4; ++q) {
        const unsigned short hh = bf16rn(x[q]);
        h[q] = hh;
        lo[q] = bf16rn(x[q] - bf16tof(hh));
    }
    *reinterpret_cast<u16x4*>(W1 + (size_t)i * 4) = h;
    *reinterpret_cast<u16x4*>(W2 + (size_t)i * 4) = lo;
}

// MFMA split-bf16 filter: per row, running min of df over all K + candidate
// list of codes with df <= rowmin + MARGIN. df error vs np-fp32 d <= 7.2e-5
// (margin = 4e-4). Winner provably always collected (stale rowmin only adds).
// Block: 64 rows; wave wv scans code stripe wv*2048. A-frags from swizzled
// LDS z-splits; B-frags streamed from W1/W2 (L2/L3).
__global__ __launch_bounds__(256, 2) void k_filter(
    const float* __restrict__ z,
    const unsigned short* __restrict__ W1, const unsigned short* __restrict__ W2,
    const float* __restrict__ A, const float* __restrict__ Cq,
    int* __restrict__ cnt_g, unsigned short* __restrict__ list_g)
{
    __shared__ unsigned short Z1t[64 * 256];  // 32 KB, [n][c] swizzled
    __shared__ unsigned short Z2t[64 * 256];  // 32 KB
    __shared__ int rowmin[64];
    __shared__ int cnt_l[64];
    __shared__ unsigned short list_l[64][CAP];

    const int t = threadIdx.x;
    const int blk = blockIdx.x;
    const int b = (blk * 64) >> 13;
    const int s0 = (blk * 64) & (THW - 1);
    const float* zb = z + (size_t)b * (CDIM * THW) + s0;

    if (t < 64) { rowmin[t] = 0x7F800000; cnt_l[t] = 0; }

    {   // stage + split z tile (coalesced reads, swizzled LDS writes)
        const int lane = t & 15;
        const int c0 = t >> 4;
#pragma unroll
        for (int it = 0; it < 16; ++it) {
            const int c = c0 + it * 16;
            float4 v = *reinterpret_cast<const float4*>(zb + (size_t)c * THW + lane * 4);
            const float vv[4] = {v.x, v.y, v.z, v.w};
#pragma unroll
            for (int q = 0; q < 4; ++q) {
                const int n = lane * 4 + q;
                const unsigned short h = bf16rn(vv[q]);
                const unsigned short l2 = bf16rn(vv[q] - bf16tof(h));
                const int off = n * 512 + ((c * 2) ^ ((n & 7) << 4));
                *(unsigned short*)((char*)Z1t + off) = h;
                *(unsigned short*)((char*)Z2t + off) = l2;
            }
        }
    }
    __syncthreads();

    const int l = t & 63;
    const int wv = t >> 6;
    const int l15 = l & 15;
    const int lg = l >> 4;
    const int stripe = wv * 2048;

    float4 Av[4];
#pragma unroll
    for (int rt = 0; rt < 4; ++rt)
        Av[rt] = *reinterpret_cast<const float4*>(A + blk * 64 + rt * 16 + lg * 4);

    for (int st = 0; st < 32; ++st) {
        const int kb = stripe + st * 64;
        f32x4 acc[4][4];
#pragma unroll
        for (int rt = 0; rt < 4; ++rt)
#pragma unroll
            for (int ct = 0; ct < 4; ++ct)
                acc[rt][ct] = (f32x4){0.f, 0.f, 0.f, 0.f};

        float cqv[4];
#pragma unroll
        for (int ct = 0; ct < 4; ++ct) cqv[ct] = Cq[kb + ct * 16 + l15];

#pragma unroll
        for (int ks = 0; ks < 8; ++ks) {
            const int cb = ks * 32 + lg * 8;
            short8v a1[4], a2[4], b1[4], b2[4];
#pragma unroll
            for (int rt = 0; rt < 4; ++rt) {
                const int n = rt * 16 + l15;
                const int off = n * 512 + ((cb * 2) ^ ((n & 7) << 4));
                a1[rt] = *(const short8v*)((const char*)Z1t + off);
                a2[rt] = *(const short8v*)((const char*)Z2t + off);
            }
#pragma unroll
            for (int ct = 0; ct < 4; ++ct) {
                const size_t wo = (size_t)(kb + ct * 16 + l15) * CDIM + cb;
                b1[ct] = *reinterpret_cast<const short8v*>(W1 + wo);
                b2[ct] = *reinterpret_cast<const short8v*>(W2 + wo);
            }
#pragma unroll
            for (int rt = 0; rt < 4; ++rt)
#pragma unroll
                for (int ct = 0; ct < 4; ++ct) {
                    acc[rt][ct] = __builtin_amdgcn_mfma_f32_16x16x32_bf16(a1[rt], b1[ct], acc[rt][ct], 0, 0, 0);
                    acc[rt][ct] = __builtin_amdgcn_mfma_f32_16x16x32_bf16(a1[rt], b2[ct], acc[rt][ct], 0, 0, 0);
                    acc[rt][ct] = __builtin_amdgcn_mfma_f32_16x16x32_bf16(a2[rt], b1[ct], acc[rt][ct], 0, 0, 0);
                }
        }

        // epilogue: df = RN(RN(A - 2*dot) + Cq); rowmin update; collect.
        // C-layout: row n = rt*16 + lg*4 + i, col code = kb + ct*16 + l15.
#pragma unroll
        for (int rt = 0; rt < 4; ++rt) {
            float dd[4][4];   // [ct][i]
            float rmv[4];
#pragma unroll
            for (int i = 0; i < 4; ++i) {
                const float Ai = ((const float*)&Av[rt])[i];
                float m = 3.0e38f;
#pragma unroll
                for (int ct = 0; ct < 4; ++ct) {
                    const float d_ = __fadd_rn(__fadd_rn(Ai, -2.0f * acc[rt][ct][i]), cqv[ct]);
                    dd[ct][i] = d_;
                    m = fminf(m, d_);
                }
#pragma unroll
                for (int mm = 1; mm < 16; mm <<= 1)
                    m = fminf(m, __shfl_xor(m, mm, 64));
                rmv[i] = m;
            }
            if (l15 == 0) {
#pragma unroll
                for (int i = 0; i < 4; ++i)
                    atomicMin(&rowmin[rt * 16 + lg * 4 + i], __float_as_int(rmv[i]));
            }
#pragma unroll
            for (int i = 0; i < 4; ++i) {
                const int nl = rt * 16 + lg * 4 + i;
                const float rm = __int_as_float(rowmin[nl]) + MARGIN;
#pragma unroll
                for (int ct = 0; ct < 4; ++ct) {
                    if (dd[ct][i] <= rm) {
                        const int slot = atomicAdd(&cnt_l[nl], 1);
                        if (slot < CAP)
                            list_l[nl][slot] = (unsigned short)(kb + ct * 16 + l15);
                    }
                }
            }
        }
    }

    __syncthreads();
    if (t < 64) {
        const int n = blk * 64 + t;
        const int c = cnt_l[t];
        cnt_g[n] = c;
        const int m = c < CAP ? c : CAP;
        for (int i = 0; i < m; ++i) list_g[(size_t)n * CAP + i] = list_l[t][i];
    }
}

// np-exact evaluation of candidates (or full scan on overflow): single
// ascending-c fmaf chain per (row, code); d = RN(RN(A-2M)+Cq); argmin with
// tie -> lowest k. Wave per row.
__device__ __forceinline__ float exact_d(const float* __restrict__ zr,
                                         const float* __restrict__ w,
                                         int k, float An, float Ck) {
    const float* wp = w + (size_t)k * CDIM;
    float m = 0.f;
#pragma unroll
    for (int c4 = 0; c4 < CDIM / 4; ++c4) {
        const float4 wv4 = *reinterpret_cast<const float4*>(wp + c4 * 4);
        m = fmaf(zr[c4 * 4 + 0], wv4.x, m);
        m = fmaf(zr[c4 * 4 + 1], wv4.y, m);
        m = fmaf(zr[c4 * 4 + 2], wv4.z, m);
        m = fmaf(zr[c4 * 4 + 3], wv4.w, m);
    }
    return __fadd_rn(__fadd_rn(An, -2.0f * m), Ck);
}

__global__ __launch_bounds__(256) void k_fix(
    const float* __restrict__ z, const float* __restrict__ w,
    const float* __restrict__ A, const float* __restrict__ Cq,
    const int* __restrict__ cnt_g, const unsigned short* __restrict__ list_g,
    float* __restrict__ idx_f)
{
    __shared__ float zrow[4][CDIM];
    const int t = threadIdx.x;
    const int wv = t >> 6;
    const int l = t & 63;
    const int n = blockIdx.x * 4 + wv;
    const int b = n >> 13;
    const int s = n & (THW - 1);

    {   // stage this wave's z row
        const float* zp = z + (size_t)b * (CDIM * THW) + s;
#pragma unroll
        for (int q = 0; q < 4; ++q)
            zrow[wv][l * 4 + q] = zp[(size_t)(l * 4 + q) * THW];
    }
    __syncthreads();

    const float An = A[n];
    const int cnt = cnt_g[n];
    float bd = 3.0e38f;
    int bk = INT_MAX;

    if (cnt > 0 && cnt <= CAP) {
        if (l < cnt) {
            const int k = list_g[(size_t)n * CAP + l];
            bd = exact_d(zrow[wv], w, k, An, Cq[k]);
            bk = k;
        }
    } else {
        for (int k = l; k < KDIM; k += 64) {
            const float d = exact_d(zrow[wv], w, k, An, Cq[k]);
            if (d < bd) { bd = d; bk = k; }   // ascending k: strict < keeps lowest
        }
    }
#pragma unroll
    for (int m = 1; m < 64; m <<= 1) {
        const float od = __shfl_xor(bd, m, 64);
        const int oi = __shfl_xor(bk, m, 64);
        if (od < bd || (od == bd && oi < bk)) { bd = od; bk = oi; }
    }
    if (l == 0) idx_f[n] = (float)bk;
}

// Gather z_q = w[idx], transpose to [B,C,T,H,W], accumulate sum((z_q - z)^2).
__global__ __launch_bounds__(256, 2) void k_out(
    const float* __restrict__ w, const float* __restrict__ z,
    const float* __restrict__ idx_f, float* __restrict__ out0,
    float* __restrict__ partial)
{
    __shared__ float q[CDIM][BNQ + 1];
    __shared__ int si[BNQ];
    __shared__ float red[256];

    const int t = threadIdx.x;
    const int blk = blockIdx.x;
    const int n0 = blk * BNQ;
    const int b = n0 >> 13;
    const int s0 = n0 & (THW - 1);

    if (t < BNQ) si[t] = (int)idx_f[n0 + t];
    __syncthreads();

    {
        const int c = t;
#pragma unroll 4
        for (int i = 0; i < BNQ; ++i)
            q[c][i] = w[(size_t)si[i] * CDIM + c];
    }
    __syncthreads();

    const int sl = t & 63;
    const int cb = t >> 6;
    float lacc = 0.f;
    const size_t base = (size_t)b * (CDIM * THW) + s0 + sl;
#pragma unroll 4
    for (int j = 0; j < 64; ++j) {
        const int c = cb * 64 + j;
        const float qv = q[c][sl];
        const size_t a = base + (size_t)c * THW;
        const float zv = z[a];
        out0[a] = qv;
        const float d = qv - zv;
        lacc = fmaf(d, d, lacc);
    }
    red[t] = lacc;
    __syncthreads();
    for (int mm = 128; mm > 0; mm >>= 1) {
        if (t < mm) red[t] += red[t + mm];
        __syncthreads();
    }
    if (t == 0) partial[blk] = red[0];
}

__global__ __launch_bounds__(256) void k_loss(const float* __restrict__ partial,
                                              float* __restrict__ out_loss) {
    __shared__ double red[256];
    const int t = threadIdx.x;
    double a = 0.0;
    for (int i = t; i < NROWS / BNQ; i += 256) a += (double)partial[i];
    __syncthreads();
    red[t] = a;
    __syncthreads();
    for (int mm = 128; mm > 0; mm >>= 1) {
        if (t < mm) red[t] += red[t + mm];
        __syncthreads();
    }
    if (t == 0) out_loss[0] = (float)(1.25 * red[0] / 8388608.0);
}

extern "C" void kernel_launch(void* const* d_in, const int* in_sizes, int n_in,
                              void* d_out, int out_size, void* d_ws, size_t ws_size,
                              hipStream_t stream) {
    const float* z = (const float*)d_in[0];
    const float* w = (const float*)d_in[1];
    float* out = (float*)d_out;

    char* ws = (char*)d_ws;
    unsigned short* W1 = (unsigned short*)ws;                // 4 MB
    unsigned short* W2 = (unsigned short*)(ws + 4194304);    // 4 MB
    float* A = (float*)(ws + 8388608);                       // 128 KB
    float* Cq = (float*)(ws + 8519680);                      // 32 KB
    int* cnt_g = (int*)(ws + 8552448);                       // 128 KB
    unsigned short* list_g = (unsigned short*)(ws + 8683520);// 1 MB
    float* partial = (float*)(ws + 9732096);                 // 2 KB

    float* out_zq = out;                 // [B,C,T,H,W] = 8388608
    float* out_loss = out + 8388608;     // scalar
    float* out_idx = out + 8388609;      // [B,T,H,W] = 32768, as float

    k_split<<<KDIM * CDIM / 4 / 256, 256, 0, stream>>>(w, W1, W2);
    k_A<<<NROWS / 256, 256, 0, stream>>>(z, A);
    k_C<<<KDIM / 256, 256, 0, stream>>>(w, Cq);
    k_filter<<<NROWS / 64, 256, 0, stream>>>(z, W1, W2, A, Cq, cnt_g, list_g);
    k_fix<<<NROWS / 4, 256, 0, stream>>>(z, w, A, Cq, cnt_g, list_g, out_idx);
    k_out<<<NROWS / BNQ, 256, 0, stream>>>(w, z, out_idx, out_zq, partial);
    k_loss<<<1, 256, 0, stream>>>(partial, out_loss);
}

// Round 10
// 4458.325 us; speedup vs baseline: 1.2646x; 1.2646x over previous
//
#include <hip/hip_runtime.h>
#include <limits.h>

#define CDIM 256
#define KDIM 8192
#define NROWS 32768
#define THW 8192
#define BNQ 64
#define CAP 16
#define MARGIN 4.0e-4f

typedef __attribute__((ext_vector_type(8))) short short8v;   // 8 bf16 (4 VGPR)
typedef __attribute__((ext_vector_type(4))) float f32x4;
typedef __attribute__((ext_vector_type(4))) unsigned short u16x4;

// ws layout (bytes):
//   [0,       4194304)  W1[k][c] bf16 hi split of w
//   [4194304, 8388608)  W2[k][c] bf16 lo split
//   [8388608, 8519680)  A[n]  np-exact (32768 f32)
//   [8519680, 8552448)  Cq[k] np-exact (8192 f32)
//   [8552448, 8683520)  cnt[n] (32768 i32)
//   [8683520, 9732096)  cand list (32768 x CAP u16)
//   [9732096, 9734144)  loss partials (512 f32)

__device__ __forceinline__ float sq_rn(float a) { return __fmul_rn(a, a); }
__device__ __forceinline__ unsigned short bf16rn(float x) {
    unsigned u = __float_as_uint(x);
    return (unsigned short)((u + 0x7FFFu + ((u >> 16) & 1u)) >> 16);
}
__device__ __forceinline__ float bf16tof(unsigned short h) {
    return __uint_as_float(((unsigned)h) << 16);
}

// numpy pairwise sum of 128 fp32 squares, AVX512 model (verified round 3).
__device__ float pairwise128_sq(const float* __restrict__ p, int stride) {
    float s[16];
#pragma unroll
    for (int l = 0; l < 16; ++l) {
        const float a0 = sq_rn(p[(l)*stride]);
        const float a1 = sq_rn(p[(16 + l) * stride]);
        const float a2 = sq_rn(p[(32 + l) * stride]);
        const float a3 = sq_rn(p[(48 + l) * stride]);
        const float a4 = sq_rn(p[(64 + l) * stride]);
        const float a5 = sq_rn(p[(80 + l) * stride]);
        const float a6 = sq_rn(p[(96 + l) * stride]);
        const float a7 = sq_rn(p[(112 + l) * stride]);
        s[l] = __fadd_rn(__fadd_rn(__fadd_rn(a0, a1), __fadd_rn(a2, a3)),
                         __fadd_rn(__fadd_rn(a4, a5), __fadd_rn(a6, a7)));
    }
    const float u0 = __fadd_rn(__fadd_rn(s[0], s[8]),  __fadd_rn(s[4], s[12]));
    const float u1 = __fadd_rn(__fadd_rn(s[1], s[9]),  __fadd_rn(s[5], s[13]));
    const float u2 = __fadd_rn(__fadd_rn(s[2], s[10]), __fadd_rn(s[6], s[14]));
    const float u3 = __fadd_rn(__fadd_rn(s[3], s[11]), __fadd_rn(s[7], s[15]));
    return __fadd_rn(__fadd_rn(u0, u2), __fadd_rn(u1, u3));
}

__global__ __launch_bounds__(256) void k_A(const float* __restrict__ z,
                                           float* __restrict__ A) {
    const int n = blockIdx.x * 256 + threadIdx.x;
    const float* zp = z + (size_t)(n >> 13) * (CDIM * THW) + (n & (THW - 1));
    const float b0 = pairwise128_sq(zp, THW);
    const float b1 = pairwise128_sq(zp + (size_t)128 * THW, THW);
    A[n] = __fadd_rn(b0, b1);
}

__global__ __launch_bounds__(256) void k_C(const float* __restrict__ w,
                                           float* __restrict__ Cq) {
    const int k = blockIdx.x * 256 + threadIdx.x;
    const float* wp = w + (size_t)k * CDIM;
    Cq[k] = __fadd_rn(pairwise128_sq(wp, 1), pairwise128_sq(wp + 128, 1));
}

// Split w -> bf16 hi/lo, row-major [k][c] (B-operand-friendly).
__global__ __launch_bounds__(256) void k_split(const float* __restrict__ w,
                                               unsigned short* __restrict__ W1,
                                               unsigned short* __restrict__ W2) {
    const int i = blockIdx.x * 256 + threadIdx.x;
    float4 v = *reinterpret_cast<const float4*>(w + (size_t)i * 4);
    const float x[4] = {v.x, v.y, v.z, v.w};
    u16x4 h, lo;
#pragma unroll
    for (int q = 0; q < 4; ++q) {
        const unsigned short hh = bf16rn(x[q]);
        h[q] = hh;
        lo[q] = bf16rn(x[q] - bf16tof(hh));
    }
    *reinterpret_cast<u16x4*>(W1 + (size_t)i * 4) = h;
    *reinterpret_cast<u16x4*>(W2 + (size_t)i * 4) = lo;
}

// MFMA split-bf16 filter. Per tile-step: df for 256 codes (64/wave) ->
// shuffle-min -> atomicMin(rowmin) -> __syncthreads -> collect with
// df <= rowmin + MARGIN. Winner always collected (any rowmin >= global min;
// margin 4e-4 >= 2*err 1.44e-4); prefix-min keeps over-collection ~ln(32).
__global__ __launch_bounds__(256, 2) void k_filter(
    const float* __restrict__ z,
    const unsigned short* __restrict__ W1, const unsigned short* __restrict__ W2,
    const float* __restrict__ A, const float* __restrict__ Cq,
    int* __restrict__ cnt_g, unsigned short* __restrict__ list_g)
{
    __shared__ unsigned short Z1t[64 * 256];  // 32 KB, [n][c] swizzled
    __shared__ unsigned short Z2t[64 * 256];  // 32 KB
    __shared__ int rowmin[64];
    __shared__ int cnt_l[64];
    __shared__ unsigned short list_l[64][CAP];

    const int t = threadIdx.x;
    const int blk = blockIdx.x;
    const int b = (blk * 64) >> 13;
    const int s0 = (blk * 64) & (THW - 1);
    const float* zb = z + (size_t)b * (CDIM * THW) + s0;

    if (t < 64) { rowmin[t] = 0x7F800000; cnt_l[t] = 0; }

    {   // stage + split z tile (coalesced reads, swizzled LDS writes)
        const int lane = t & 15;
        const int c0 = t >> 4;
#pragma unroll
        for (int it = 0; it < 16; ++it) {
            const int c = c0 + it * 16;
            float4 v = *reinterpret_cast<const float4*>(zb + (size_t)c * THW + lane * 4);
            const float vv[4] = {v.x, v.y, v.z, v.w};
#pragma unroll
            for (int q = 0; q < 4; ++q) {
                const int n = lane * 4 + q;
                const unsigned short h = bf16rn(vv[q]);
                const unsigned short l2 = bf16rn(vv[q] - bf16tof(h));
                const int off = n * 512 + ((c * 2) ^ ((n & 7) << 4));
                *(unsigned short*)((char*)Z1t + off) = h;
                *(unsigned short*)((char*)Z2t + off) = l2;
            }
        }
    }
    __syncthreads();

    const int l = t & 63;
    const int wv = t >> 6;
    const int l15 = l & 15;
    const int lg = l >> 4;
    const int stripe = wv * 2048;

    float4 Av[4];
#pragma unroll
    for (int rt = 0; rt < 4; ++rt)
        Av[rt] = *reinterpret_cast<const float4*>(A + blk * 64 + rt * 16 + lg * 4);

    for (int st = 0; st < 32; ++st) {
        const int kb = stripe + st * 64;
        f32x4 acc[4][4];
#pragma unroll
        for (int rt = 0; rt < 4; ++rt)
#pragma unroll
            for (int ct = 0; ct < 4; ++ct)
                acc[rt][ct] = (f32x4){0.f, 0.f, 0.f, 0.f};

        float cqv[4];
#pragma unroll
        for (int ct = 0; ct < 4; ++ct) cqv[ct] = Cq[kb + ct * 16 + l15];

#pragma unroll
        for (int ks = 0; ks < 8; ++ks) {
            const int cb = ks * 32 + lg * 8;
            short8v a1[4], a2[4], b1[4], b2[4];
#pragma unroll
            for (int rt = 0; rt < 4; ++rt) {
                const int n = rt * 16 + l15;
                const int off = n * 512 + ((cb * 2) ^ ((n & 7) << 4));
                a1[rt] = *(const short8v*)((const char*)Z1t + off);
                a2[rt] = *(const short8v*)((const char*)Z2t + off);
            }
#pragma unroll
            for (int ct = 0; ct < 4; ++ct) {
                const size_t wo = (size_t)(kb + ct * 16 + l15) * CDIM + cb;
                b1[ct] = *reinterpret_cast<const short8v*>(W1 + wo);
                b2[ct] = *reinterpret_cast<const short8v*>(W2 + wo);
            }
#pragma unroll
            for (int rt = 0; rt < 4; ++rt)
#pragma unroll
                for (int ct = 0; ct < 4; ++ct) {
                    acc[rt][ct] = __builtin_amdgcn_mfma_f32_16x16x32_bf16(a1[rt], b1[ct], acc[rt][ct], 0, 0, 0);
                    acc[rt][ct] = __builtin_amdgcn_mfma_f32_16x16x32_bf16(a1[rt], b2[ct], acc[rt][ct], 0, 0, 0);
                    acc[rt][ct] = __builtin_amdgcn_mfma_f32_16x16x32_bf16(a2[rt], b1[ct], acc[rt][ct], 0, 0, 0);
                }
        }

        // df = RN(RN(A - 2*dot) + Cq). C-layout: row = rt*16 + lg*4 + i,
        // col code = kb + ct*16 + l15.
        float dd[4][4][4];   // [rt][ct][i]
#pragma unroll
        for (int rt = 0; rt < 4; ++rt) {
#pragma unroll
            for (int i = 0; i < 4; ++i) {
                const float Ai = ((const float*)&Av[rt])[i];
                float m = 3.0e38f;
#pragma unroll
                for (int ct = 0; ct < 4; ++ct) {
                    const float d_ = __fadd_rn(__fadd_rn(Ai, -2.0f * acc[rt][ct][i]), cqv[ct]);
                    dd[rt][ct][i] = d_;
                    m = fminf(m, d_);
                }
#pragma unroll
                for (int mm = 1; mm < 16; mm <<= 1)
                    m = fminf(m, __shfl_xor(m, mm, 64));
                if (l15 == 0)
                    atomicMin(&rowmin[rt * 16 + lg * 4 + i], __float_as_int(m));
            }
        }
        __syncthreads();   // prefix-min (all 4 stripes, tiles 0..st) published

        // collect vs synced prefix min
#pragma unroll
        for (int rt = 0; rt < 4; ++rt) {
#pragma unroll
            for (int i = 0; i < 4; ++i) {
                const int nl = rt * 16 + lg * 4 + i;
                const float rm = __int_as_float(rowmin[nl]) + MARGIN;
#pragma unroll
                for (int ct = 0; ct < 4; ++ct) {
                    if (dd[rt][ct][i] <= rm) {
                        const int slot = atomicAdd(&cnt_l[nl], 1);
                        if (slot < CAP)
                            list_l[nl][slot] = (unsigned short)(kb + ct * 16 + l15);
                    }
                }
            }
        }
    }

    __syncthreads();
    if (t < 64) {
        const int n = blk * 64 + t;
        const int c = cnt_l[t];
        cnt_g[n] = c;
        const int m = c < CAP ? c : CAP;
        for (int i = 0; i < m; ++i) list_g[(size_t)n * CAP + i] = list_l[t][i];
    }
}

// np-exact evaluation of candidates (or full scan on overflow): single
// ascending-c fmaf chain; d = RN(RN(A-2M)+Cq); argmin tie -> lowest k.
__device__ __forceinline__ float exact_d(const float* __restrict__ zr,
                                         const float* __restrict__ w,
                                         int k, float An, float Ck) {
    const float* wp = w + (size_t)k * CDIM;
    float m = 0.f;
#pragma unroll
    for (int c4 = 0; c4 < CDIM / 4; ++c4) {
        const float4 wv4 = *reinterpret_cast<const float4*>(wp + c4 * 4);
        m = fmaf(zr[c4 * 4 + 0], wv4.x, m);
        m = fmaf(zr[c4 * 4 + 1], wv4.y, m);
        m = fmaf(zr[c4 * 4 + 2], wv4.z, m);
        m = fmaf(zr[c4 * 4 + 3], wv4.w, m);
    }
    return __fadd_rn(__fadd_rn(An, -2.0f * m), Ck);
}

__global__ __launch_bounds__(256) void k_fix(
    const float* __restrict__ z, const float* __restrict__ w,
    const float* __restrict__ A, const float* __restrict__ Cq,
    const int* __restrict__ cnt_g, const unsigned short* __restrict__ list_g,
    float* __restrict__ idx_f)
{
    __shared__ float zrow[4][CDIM];
    const int t = threadIdx.x;
    const int wv = t >> 6;
    const int l = t & 63;
    const int n = blockIdx.x * 4 + wv;
    const int b = n >> 13;
    const int s = n & (THW - 1);

    {   // stage this wave's z row
        const float* zp = z + (size_t)b * (CDIM * THW) + s;
#pragma unroll
        for (int q = 0; q < 4; ++q)
            zrow[wv][l * 4 + q] = zp[(size_t)(l * 4 + q) * THW];
    }
    __syncthreads();

    const float An = A[n];
    const int cnt = cnt_g[n];
    float bd = 3.0e38f;
    int bk = INT_MAX;

    if (cnt > 0 && cnt <= CAP) {
        if (l < cnt) {
            const int k = list_g[(size_t)n * CAP + l];
            bd = exact_d(zrow[wv], w, k, An, Cq[k]);
            bk = k;
        }
    } else {
        for (int k = l; k < KDIM; k += 64) {
            const float d = exact_d(zrow[wv], w, k, An, Cq[k]);
            if (d < bd) { bd = d; bk = k; }   // ascending k: strict < keeps lowest
        }
    }
#pragma unroll
    for (int m = 1; m < 64; m <<= 1) {
        const float od = __shfl_xor(bd, m, 64);
        const int oi = __shfl_xor(bk, m, 64);
        if (od < bd || (od == bd && oi < bk)) { bd = od; bk = oi; }
    }
    if (l == 0) idx_f[n] = (float)bk;
}

// Gather z_q = w[idx], transpose to [B,C,T,H,W], accumulate sum((z_q - z)^2).
__global__ __launch_bounds__(256, 2) void k_out(
    const float* __restrict__ w, const float* __restrict__ z,
    const float* __restrict__ idx_f, float* __restrict__ out0,
    float* __restrict__ partial)
{
    __shared__ float q[CDIM][BNQ + 1];
    __shared__ int si[BNQ];
    __shared__ float red[256];

    const int t = threadIdx.x;
    const int blk = blockIdx.x;
    const int n0 = blk * BNQ;
    const int b = n0 >> 13;
    const int s0 = n0 & (THW - 1);

    if (t < BNQ) si[t] = (int)idx_f[n0 + t];
    __syncthreads();

    {
        const int c = t;
#pragma unroll 4
        for (int i = 0; i < BNQ; ++i)
            q[c][i] = w[(size_t)si[i] * CDIM + c];
    }
    __syncthreads();

    const int sl = t & 63;
    const int cb = t >> 6;
    float lacc = 0.f;
    const size_t base = (size_t)b * (CDIM * THW) + s0 + sl;
#pragma unroll 4
    for (int j = 0; j < 64; ++j) {
        const int c = cb * 64 + j;
        const float qv = q[c][sl];
        const size_t a = base + (size_t)c * THW;
        const float zv = z[a];
        out0[a] = qv;
        const float d = qv - zv;
        lacc = fmaf(d, d, lacc);
    }
    red[t] = lacc;
    __syncthreads();
    for (int mm = 128; mm > 0; mm >>= 1) {
        if (t < mm) red[t] += red[t + mm];
        __syncthreads();
    }
    if (t == 0) partial[blk] = red[0];
}

__global__ __launch_bounds__(256) void k_loss(const float* __restrict__ partial,
                                              float* __restrict__ out_loss) {
    __shared__ double red[256];
    const int t = threadIdx.x;
    double a = 0.0;
    for (int i = t; i < NROWS / BNQ; i += 256) a += (double)partial[i];
    red[t] = a;
    __syncthreads();
    for (int mm = 128; mm > 0; mm >>= 1) {
        if (t < mm) red[t] += red[t + mm];
        __syncthreads();
    }
    if (t == 0) out_loss[0] = (float)(1.25 * red[0] / 8388608.0);
}

extern "C" void kernel_launch(void* const* d_in, const int* in_sizes, int n_in,
                              void* d_out, int out_size, void* d_ws, size_t ws_size,
                              hipStream_t stream) {
    const float* z = (const float*)d_in[0];
    const float* w = (const float*)d_in[1];
    float* out = (float*)d_out;

    char* ws = (char*)d_ws;
    unsigned short* W1 = (unsigned short*)ws;                // 4 MB
    unsigned short* W2 = (unsigned short*)(ws + 4194304);    // 4 MB
    float* A = (float*)(ws + 8388608);                       // 128 KB
    float* Cq = (float*)(ws + 8519680);                      // 32 KB
    int* cnt_g = (int*)(ws + 8552448);                       // 128 KB
    unsigned short* list_g = (unsigned short*)(ws + 8683520);// 1 MB
    float* partial = (float*)(ws + 9732096);                 // 2 KB

    float* out_zq = out;                 // [B,C,T,H,W] = 8388608
    float* out_loss = out + 8388608;     // scalar
    float* out_idx = out + 8388609;      // [B,T,H,W] = 32768, as float

    k_split<<<KDIM * CDIM / 4 / 256, 256, 0, stream>>>(w, W1, W2);
    k_A<<<NROWS / 256, 256, 0, stream>>>(z, A);
    k_C<<<KDIM / 256, 256, 0, stream>>>(w, Cq);
    k_filter<<<NROWS / 64, 256, 0, stream>>>(z, W1, W2, A, Cq, cnt_g, list_g);
    k_fix<<<NROWS / 4, 256, 0, stream>>>(z, w, A, Cq, cnt_g, list_g, out_idx);
    k_out<<<NROWS / BNQ, 256, 0, stream>>>(w, z, out_idx, out_zq, partial);
    k_loss<<<1, 256, 0, stream>>>(partial, out_loss);
}

// Round 12
// 1435.408 us; speedup vs baseline: 3.9279x; 3.1060x over previous
//
#include <hip/hip_runtime.h>
#include <limits.h>

#define CDIM 256
#define KDIM 8192
#define NROWS 32768
#define THW 8192
#define BN 64      // argmin rows per block (4 waves x 16 rows)
#define BNQ 64     // k_out rows per block

typedef __attribute__((ext_vector_type(2))) float f32x2;

// ws layout (bytes):
//   [0,       8388608)  wT[c][k] = w[k][c]  (256 x 8192 f32)
//   [8388608, 8519680)  A[n]  (32768 f32)
//   [8519680, 8552448)  Cq[k] (8192 f32)
//   [8552448, 8683520)  idx_i (32768 i32)
//   [8683520, 8685568)  loss partials (512 f32)

__device__ __forceinline__ float sq_rn(float a) { return __fmul_rn(a, a); }

// numpy pairwise sum of 128 fp32 squares, AVX512 model (verified round 3).
__device__ float pairwise128_sq(const float* __restrict__ p, int stride) {
    float s[16];
#pragma unroll
    for (int l = 0; l < 16; ++l) {
        const float a0 = sq_rn(p[(l)*stride]);
        const float a1 = sq_rn(p[(16 + l) * stride]);
        const float a2 = sq_rn(p[(32 + l) * stride]);
        const float a3 = sq_rn(p[(48 + l) * stride]);
        const float a4 = sq_rn(p[(64 + l) * stride]);
        const float a5 = sq_rn(p[(80 + l) * stride]);
        const float a6 = sq_rn(p[(96 + l) * stride]);
        const float a7 = sq_rn(p[(112 + l) * stride]);
        s[l] = __fadd_rn(__fadd_rn(__fadd_rn(a0, a1), __fadd_rn(a2, a3)),
                         __fadd_rn(__fadd_rn(a4, a5), __fadd_rn(a6, a7)));
    }
    const float u0 = __fadd_rn(__fadd_rn(s[0], s[8]),  __fadd_rn(s[4], s[12]));
    const float u1 = __fadd_rn(__fadd_rn(s[1], s[9]),  __fadd_rn(s[5], s[13]));
    const float u2 = __fadd_rn(__fadd_rn(s[2], s[10]), __fadd_rn(s[6], s[14]));
    const float u3 = __fadd_rn(__fadd_rn(s[3], s[11]), __fadd_rn(s[7], s[15]));
    return __fadd_rn(__fadd_rn(u0, u2), __fadd_rn(u1, u3));
}

__global__ __launch_bounds__(256) void k_A(const float* __restrict__ z,
                                           float* __restrict__ A) {
    const int n = blockIdx.x * 256 + threadIdx.x;
    const float* zp = z + (size_t)(n >> 13) * (CDIM * THW) + (n & (THW - 1));
    const float b0 = pairwise128_sq(zp, THW);
    const float b1 = pairwise128_sq(zp + (size_t)128 * THW, THW);
    A[n] = __fadd_rn(b0, b1);
}

__global__ __launch_bounds__(256) void k_C(const float* __restrict__ w,
                                           float* __restrict__ Cq) {
    const int k = blockIdx.x * 256 + threadIdx.x;
    const float* wp = w + (size_t)k * CDIM;
    Cq[k] = __fadd_rn(pairwise128_sq(wp, 1), pairwise128_sq(wp + 128, 1));
}

// Transpose w[k][c] -> wT[c][k] via 64x64 LDS tiles.
__global__ __launch_bounds__(256) void k_T(const float* __restrict__ w,
                                           float* __restrict__ wT) {
    __shared__ float tile[64][65];
    const int t = threadIdx.x;
    const int kt = blockIdx.x >> 2;
    const int ct = blockIdx.x & 3;
    const int k0 = kt * 64, c0 = ct * 64;
    const int rg = t >> 4, cl = (t & 15) * 4;
#pragma unroll
    for (int i = 0; i < 4; ++i) {
        const int r = rg + i * 16;
        float4 v = *reinterpret_cast<const float4*>(w + (size_t)(k0 + r) * CDIM + c0 + cl);
        tile[r][cl] = v.x; tile[r][cl + 1] = v.y;
        tile[r][cl + 2] = v.z; tile[r][cl + 3] = v.w;
    }
    __syncthreads();
#pragma unroll
    for (int i = 0; i < 4; ++i) {
        const int cr = rg + i * 16;
        float4 o;
        o.x = tile[cl + 0][cr]; o.y = tile[cl + 1][cr];
        o.z = tile[cl + 2][cr]; o.w = tile[cl + 3][cr];
        *reinterpret_cast<float4*>(wT + (size_t)(c0 + cr) * KDIM + k0 + cl) = o;
    }
}

// p = kt*256 + c linear schedule position, 0..4095.
// w: lane owns k = kt*512 + lane*8 .. +7 (contiguous 64B/lane, coalesced).
// z: wave-uniform LDS broadcast of this wave's 16 rows.
#define PREF_W(buf, p) { \
    const int pp_ = (p) < 4095 ? (p) : 4095; \
    const float* ap_ = wT + ((size_t)(pp_ & 255) << 13) + ((pp_ >> 8) << 9) + lane8; \
    buf[0] = *(const float4*)(ap_); \
    buf[1] = *(const float4*)(ap_ + 4); }

#define PREF_Z(buf, p) { \
    const float* zp_ = &zt[(p) & 255][wv16]; \
    buf[0] = *(const float4*)(zp_); \
    buf[1] = *(const float4*)(zp_ + 4); \
    buf[2] = *(const float4*)(zp_ + 8); \
    buf[3] = *(const float4*)(zp_ + 12); }

// Packed-pair FMA: each half is an independent IEEE-RN fp32 fma, so the
// per-(n,k) single ascending-c chain is bit-identical to scalar fmaf.
// __builtin_elementwise_fma lowers to per-element llvm.fma -> backend can
// select v_pk_fma_f32 (VOP3P) halving VALU issue; scalar fallback identical.
#if __has_builtin(__builtin_elementwise_fma)
#define PKFMA(accv, zz, wp) accv = __builtin_elementwise_fma(zz, wp, accv)
#else
#define PKFMA(accv, zz, wp) { accv[0] = fmaf(zz[0], wp[0], accv[0]); \
                              accv[1] = fmaf(zz[1], wp[1], accv[1]); }
#endif

#define COMP(wb_, zb_) { \
    const f32x2 wp_[4] = {{wb_[0].x, wb_[0].y}, {wb_[0].z, wb_[0].w}, \
                          {wb_[1].x, wb_[1].y}, {wb_[1].z, wb_[1].w}}; \
    const float zr_[16] = {zb_[0].x, zb_[0].y, zb_[0].z, zb_[0].w, \
                           zb_[1].x, zb_[1].y, zb_[1].z, zb_[1].w, \
                           zb_[2].x, zb_[2].y, zb_[2].z, zb_[2].w, \
                           zb_[3].x, zb_[3].y, zb_[3].z, zb_[3].w}; \
    _Pragma("unroll") \
    for (int r_ = 0; r_ < 16; ++r_) { \
        const f32x2 zz_ = {zr_[r_], zr_[r_]}; \
        _Pragma("unroll") \
        for (int jp_ = 0; jp_ < 4; ++jp_) \
            PKFMA(acc[r_][jp_], zz_, wp_[jp_]); \
    } }

// Fused scores GEMM + argmin, np-fp32-exact (verified round 3):
// single ascending-c fmaf chain; d = RN(RN(A-2M)+Cq); argmin ties->lowest k.
// 16 rows x 8 cols per thread; w register-streamed from wT through L1/L2;
// zero barriers in the main loop. (= round-6 verified structure + packed FMA)
__global__ __launch_bounds__(256, 2) void k_argmin(
    const float* __restrict__ z, const float* __restrict__ wT,
    const float* __restrict__ A, const float* __restrict__ Cq,
    float* __restrict__ idx_f, int* __restrict__ idx_i)
{
    __shared__ float zt[CDIM][BN];   // 64 KB resident z tile [c][n]

    const int t = threadIdx.x;
    const int blk = blockIdx.x;
    const int b = (blk * BN) >> 13;
    const int s0 = (blk * BN) & (THW - 1);
    const float* zb = z + (size_t)b * (CDIM * THW) + s0;

    {   // load z tile (coalesced, once)
        const int lane = t & 15;
        const int c0 = t >> 4;
#pragma unroll
        for (int it = 0; it < 16; ++it) {
            const int c = c0 + it * 16;
            float4 v = *reinterpret_cast<const float4*>(zb + (size_t)c * THW + lane * 4);
            *reinterpret_cast<float4*>(&zt[c][lane * 4]) = v;
        }
    }
    __syncthreads();   // the only barrier

    const int lane8 = (t & 63) * 8;   // k-offset within k-tile
    const int wv16 = (t >> 6) * 16;   // row-offset within block
    const int nbase = blk * BN + wv16;

    float best[16];
    int bidx[16];
#pragma unroll
    for (int r = 0; r < 16; ++r) { best[r] = 3.0e38f; bidx[r] = INT_MAX; }

    float4 wa[2], wb[2], za[4], zb4[4];
    PREF_W(wa, 0); PREF_Z(za, 0);

    for (int kt = 0; kt < 16; ++kt) {
        f32x2 acc[16][4];
#pragma unroll
        for (int r = 0; r < 16; ++r)
#pragma unroll
            for (int jp = 0; jp < 4; ++jp) acc[r][jp] = (f32x2){0.f, 0.f};

        const int pbase = kt * 256;
        for (int c2 = 0; c2 < 256; c2 += 2) {
            PREF_W(wb, pbase + c2 + 1); PREF_Z(zb4, pbase + c2 + 1);
            COMP(wa, za);
            PREF_W(wa, pbase + c2 + 2); PREF_Z(za, pbase + c2 + 2);
            COMP(wb, zb4);
        }

        // epilogue: d = RN(RN(A - 2M) + C); ascending k; strict < (np.argmin)
        const float4 cq0 = *reinterpret_cast<const float4*>(Cq + kt * 512 + lane8);
        const float4 cq1 = *reinterpret_cast<const float4*>(Cq + kt * 512 + lane8 + 4);
        const float cv[8] = {cq0.x, cq0.y, cq0.z, cq0.w, cq1.x, cq1.y, cq1.z, cq1.w};
        float Ar[16];
#pragma unroll
        for (int r = 0; r < 16; ++r) Ar[r] = A[nbase + r];
#pragma unroll
        for (int j = 0; j < 8; ++j) {
            const int kg = kt * 512 + lane8 + j;
#pragma unroll
            for (int r = 0; r < 16; ++r) {
                const float av = acc[r][j >> 1][j & 1];
                const float dd = __fadd_rn(__fadd_rn(Ar[r], -2.0f * av), cv[j]);
                if (dd < best[r]) { best[r] = dd; bidx[r] = kg; }
            }
        }
    }

    // Merge across the 64 lanes (each lane had a disjoint k-set); ties -> lower k.
#pragma unroll
    for (int m = 1; m < 64; m <<= 1) {
#pragma unroll
        for (int r = 0; r < 16; ++r) {
            const float od = __shfl_xor(best[r], m, 64);
            const int oi = __shfl_xor(bidx[r], m, 64);
            if (od < best[r] || (od == best[r] && oi < bidx[r])) {
                best[r] = od; bidx[r] = oi;
            }
        }
    }
    if ((t & 63) == 0) {
#pragma unroll
        for (int r = 0; r < 16; ++r) {
            const int n = nbase + r;
            idx_f[n] = (float)bidx[r];
            idx_i[n] = bidx[r];
        }
    }
}

// Gather z_q = w[idx], transpose to [B,C,T,H,W], accumulate sum((z_q - z)^2).
__global__ __launch_bounds__(256, 2) void k_out(
    const float* __restrict__ w, const float* __restrict__ z,
    const int* __restrict__ idx, float* __restrict__ out0,
    float* __restrict__ partial)
{
    __shared__ float q[CDIM][BNQ + 1];
    __shared__ int si[BNQ];
    __shared__ float red[256];

    const int t = threadIdx.x;
    const int blk = blockIdx.x;
    const int n0 = blk * BNQ;
    const int b = n0 >> 13;
    const int s0 = n0 & (THW - 1);

    if (t < BNQ) si[t] = idx[n0 + t];
    __syncthreads();

    {
        const int c = t;
#pragma unroll 4
        for (int i = 0; i < BNQ; ++i)
            q[c][i] = w[(size_t)si[i] * CDIM + c];
    }
    __syncthreads();

    const int sl = t & 63;
    const int cb = t >> 6;
    float lacc = 0.f;
    const size_t base = (size_t)b * (CDIM * THW) + s0 + sl;
#pragma unroll 4
    for (int j = 0; j < 64; ++j) {
        const int c = cb * 64 + j;
        const float qv = q[c][sl];
        const size_t a = base + (size_t)c * THW;
        const float zv = z[a];
        out0[a] = qv;
        const float d = qv - zv;
        lacc = fmaf(d, d, lacc);
    }
    red[t] = lacc;
    __syncthreads();
    for (int mm = 128; mm > 0; mm >>= 1) {
        if (t < mm) red[t] += red[t + mm];
        __syncthreads();
    }
    if (t == 0) partial[blk] = red[0];
}

__global__ __launch_bounds__(256) void k_loss(const float* __restrict__ partial,
                                              float* __restrict__ out_loss) {
    __shared__ double red[256];
    const int t = threadIdx.x;
    double a = 0.0;
    for (int i = t; i < NROWS / BNQ; i += 256) a += (double)partial[i];
    red[t] = a;
    __syncthreads();
    for (int mm = 128; mm > 0; mm >>= 1) {
        if (t < mm) red[t] += red[t + mm];
        __syncthreads();
    }
    if (t == 0) out_loss[0] = (float)(1.25 * red[0] / 8388608.0);
}

extern "C" void kernel_launch(void* const* d_in, const int* in_sizes, int n_in,
                              void* d_out, int out_size, void* d_ws, size_t ws_size,
                              hipStream_t stream) {
    const float* z = (const float*)d_in[0];
    const float* w = (const float*)d_in[1];
    float* out = (float*)d_out;

    char* ws = (char*)d_ws;
    float* wT = (float*)ws;                     // 8 MB
    float* A = (float*)(ws + 8388608);          // 128 KB
    float* Cq = (float*)(ws + 8519680);         // 32 KB
    int* idxi = (int*)(ws + 8552448);           // 128 KB
    float* partial = (float*)(ws + 8683520);    // 2 KB

    float* out_zq = out;                 // [B,C,T,H,W] = 8388608
    float* out_loss = out + 8388608;     // scalar
    float* out_idx = out + 8388609;      // [B,T,H,W] = 32768, as float

    k_T<<<512, 256, 0, stream>>>(w, wT);
    k_A<<<NROWS / 256, 256, 0, stream>>>(z, A);
    k_C<<<KDIM / 256, 256, 0, stream>>>(w, Cq);
    k_argmin<<<NROWS / BN, 256, 0, stream>>>(z, wT, A, Cq, out_idx, idxi);
    k_out<<<NROWS / BNQ, 256, 0, stream>>>(w, z, idxi, out_zq, partial);
    k_loss<<<1, 256, 0, stream>>>(partial, out_loss);
}